// Round 13
// baseline (776.965 us; speedup 1.0000x reference)
//
#include <hip/hip_runtime.h>
#include <hip/hip_cooperative_groups.h>

namespace cg = cooperative_groups;

#define NCLUST 256
#define NFEAT  64
#define NBLK   256      // grid size == #CUs; 1 block/CU (cooperative)
#define BIGF   1e30f

#define SUMSC  16777216.0f      // 2^24 (pow2 mul = exact exponent shift)
#define SSQSC  2097152.0f       // 2^21
#define INV_SUMSC (1.0 / 16777216.0)
#define INV_SSQSC (1.0 / 2097152.0)

typedef __attribute__((ext_vector_type(8))) short  short8v;   // 8 x bf16
typedef __attribute__((ext_vector_type(4))) float  float4v;

// ---- static device scratch (rewritten fully every call) ----
__device__ __align__(16) unsigned g_psum[(size_t)NCLUST * NBLK * NFEAT]; // 16.7MB (permuted)
__device__ __align__(16) unsigned g_pssq[(size_t)NCLUST * NBLK * NFEAT]; // 16.7MB (permuted)
__device__ unsigned g_pcnt[NCLUST * NBLK * 8];
__device__ float  g_cnt[NCLUST];
__device__ __align__(16) double g_means64T[NFEAT * NCLUST];   // transposed [f][c]
__device__ __align__(16) unsigned short g_tmplbf[NCLUST * NFEAT]; // swizzled bf16
__device__ double g_tn64[NCLUST];
__device__ double g_std64[NCLUST];
__device__ float  g_std32[NCLUST];
__device__ float2 g_ktab[NCLUST];         // (tn_f32, thr2_f32 or -1 if invalid)
__device__ int    g_valid[NCLUST];
__device__ int    g_list[1000000];
__device__ int    g_nlist;

static __device__ __forceinline__ unsigned short f2bf(float x) {
    union { float f; unsigned u; } v; v.f = x;
    unsigned r = v.u + 0x7fffu + ((v.u >> 16) & 1u);   // RNE
    return (unsigned short)(r >> 16);
}

// LDS union: phases reuse the same 136 KB
union SMem {
    struct { unsigned lsum[NCLUST * NFEAT]; unsigned lssq[NCLUST * NFEAT];
             unsigned lcnt[NCLUST * 8]; } a;                       // 136 KiB (stats)
    struct { long long red[4][NFEAT]; long long redq[4][NFEAT];
             double smean[NFEAT]; double sh_cnt; } b;              // finalize
    struct { float svals[NCLUST]; int svalid[NCLUST]; float mred[2]; } m; // median
    struct { unsigned short tml[NCLUST * NFEAT]; float2 ktab[NCLUST]; } c; // 34 KiB (match)
};

__global__ __launch_bounds__(1024, 1) void kfused(const float* __restrict__ spikes,
                                                  const int* __restrict__ sidx,
                                                  const unsigned char* __restrict__ midx,
                                                  float* __restrict__ out, int n) {
    cg::grid_group grid = cg::this_grid();
    __shared__ SMem sm;

    const int tid  = threadIdx.x;
    const int bid  = blockIdx.x;
    const int lane = tid & 63;
    const int wave = tid >> 6;                  // 0..15

    // ================= PHASE A: segment stats (u32 fixed-point, fire-and-forget) =======
    for (int idx = tid; idx < NCLUST * NFEAT; idx += 1024) { sm.a.lsum[idx] = 0u; sm.a.lssq[idx] = 0u; }
    for (int idx = tid; idx < NCLUST * 8; idx += 1024) sm.a.lcnt[idx] = 0u;
    if (bid == 0 && tid == 0) g_nlist = 0;
    __syncthreads();

    {
        const int half = lane >> 5;             // which spike of the pair
        const int m    = lane & 31;             // feature pair (feats m, 32+m permuted)
        const int per  = (n + NBLK - 1) / NBLK;
        const int s0   = bid * per;
        const int s1   = min(n, s0 + per);

        for (int ib = s0 + wave * 32; ib < s1; ib += 16 * 32) {
            float2 v[16]; int cc[16];
            #pragma unroll
            for (int p = 0; p < 16; ++p) {
                int i  = ib + p * 2 + half;
                int rc = (i < s1) ? i : (s1 - 1);
                v[p]  = *(const float2*)(spikes + (size_t)rc * NFEAT + m * 2);
                cc[p] = (i < s1) ? sidx[i] : 0;
            }
            #pragma unroll
            for (int p = 0; p < 16; ++p) {
                int c = cc[p];
                if (c != 0) {
                    int base = (c - 1) * NFEAT;
                    atomicAdd(&sm.a.lsum[base + m],      (unsigned)__float2int_rn(v[p].x * SUMSC));
                    atomicAdd(&sm.a.lsum[base + 32 + m], (unsigned)__float2int_rn(v[p].y * SUMSC));
                    atomicAdd(&sm.a.lssq[base + m],      (unsigned)__float2int_rn(v[p].x * v[p].x * SSQSC));
                    atomicAdd(&sm.a.lssq[base + 32 + m], (unsigned)__float2int_rn(v[p].y * v[p].y * SSQSC));
                    if (m == 0) atomicAdd(&sm.a.lcnt[(c - 1) * 8 + (wave & 7)], 1u);
                }
            }
        }
        __syncthreads();
        for (int idx = tid; idx < NCLUST * NFEAT; idx += 1024) {
            int c = idx >> 6, w = idx & 63;
            g_psum[((size_t)c * NBLK + bid) * NFEAT + w] = sm.a.lsum[idx];   // stays permuted
            g_pssq[((size_t)c * NBLK + bid) * NFEAT + w] = sm.a.lssq[idx];
        }
        for (int idx = tid; idx < NCLUST * 8; idx += 1024) {
            int c = idx >> 3, k = idx & 7;
            g_pcnt[(c * NBLK + bid) * 8 + k] = sm.a.lcnt[idx];
        }
    }
    __threadfence();     // device-scope visibility of g_psum/g_pssq across XCDs
    grid.sync();

    // ================= PHASE B: per-cluster finalize (cluster = bid) ====================
    // R12 bug fixed: barriers are UNCONDITIONAL (were inside `if(tid<256)`).
    {
        const int c = bid;
        const int f = tid & 63, j = tid >> 6;
        const int w = ((f & 1) << 5) | (f >> 1);    // permuted word for feature f

        if (tid < 256) {
            long long acc = 0, accq = 0;
            for (int b = j; b < NBLK; b += 4) {
                acc  += (int)g_psum[((size_t)c * NBLK + b) * NFEAT + w];
                accq += (int)g_pssq[((size_t)c * NBLK + b) * NFEAT + w];
            }
            sm.b.red[j][f] = acc; sm.b.redq[j][f] = accq;
        }
        if (tid < 64) {
            unsigned cn = 0u;
            for (int e = tid; e < NBLK * 8; e += 64)
                cn += g_pcnt[c * NBLK * 8 + e];
            #pragma unroll
            for (int o = 32; o; o >>= 1) cn += __shfl_xor(cn, o);
            if (tid == 0) sm.b.sh_cnt = (double)cn;
        }
        __syncthreads();                              // ALL 1024 threads

        if (tid < NFEAT) {
            long long tot = ((sm.b.red[0][f] + sm.b.red[1][f]) + sm.b.red[2][f]) + sm.b.red[3][f];
            double cnt = sm.b.sh_cnt;
            double mean = (cnt > 0.0) ? ((double)tot * INV_SUMSC) / cnt : 0.0;
            g_means64T[f * NCLUST + c] = mean;
            sm.b.smean[f] = mean;
            sm.b.redq[0][f] = ((sm.b.redq[0][f] + sm.b.redq[1][f]) + sm.b.redq[2][f]) + sm.b.redq[3][f];
            unsigned short hb = f2bf((float)mean);
            unsigned g = (unsigned)(f >> 3);
            unsigned byteoff = (unsigned)c * 128u
                             + (((g * 16u) ^ (((unsigned)c & 7u) << 4)) + (unsigned)(f & 7) * 2u);
            *(unsigned short*)((char*)g_tmplbf + byteoff) = hb;
        }
        __syncthreads();                              // ALL 1024 threads

        if (tid == 0) {
            double tn = 0.0; long long qs = 0;
            for (int q = 0; q < NFEAT; ++q) { tn += sm.b.smean[q] * sm.b.smean[q]; qs += sm.b.redq[0][q]; }
            double cnt = sm.b.sh_cnt;
            double var = (cnt > 0.0) ? ((double)qs * INV_SSQSC) / cnt - tn : 0.0;
            if (var < 0.0) var = 0.0;
            double sd = sqrt(var);
            g_tn64[c] = tn; g_std64[c] = sd; g_std32[c] = (float)sd;
            g_cnt[c] = (float)cnt;
        }
    }
    __threadfence();
    grid.sync();

    // ================= PHASE Bm: median + validity + ktab (block 0, block-wide barriers) =
    if (bid == 0) {
        if (tid < 256) {
            if (tid == 0) { sm.m.mred[0] = 0.f; sm.m.mred[1] = 0.f; }
            sm.m.svals[tid]  = g_std32[tid];
            sm.m.svalid[tid] = (g_cnt[tid] > 0.f) ? 1 : 0;
        }
        __syncthreads();
        if (tid < 256) {
            float sd = sm.m.svals[tid];
            int   v0 = sm.m.svalid[tid];
            int m = 0, rank = 0;
            for (int jj = 0; jj < NCLUST; ++jj) {
                if (sm.m.svalid[jj]) {
                    ++m;
                    float sj = sm.m.svals[jj];
                    if (sj < sd || (sj == sd && jj < tid)) ++rank;
                }
            }
            if (v0) {
                if (rank == (m - 1) / 2) sm.m.mred[0] = sd;
                if (rank == m / 2)       sm.m.mred[1] = sd;
            }
        }
        __syncthreads();
        if (tid < 256) {
            float med = 0.5f * (sm.m.mred[0] + sm.m.mred[1]);
            float sd  = sm.m.svals[tid];
            int   v0  = sm.m.svalid[tid];
            int valid = v0 && (sd <= 3.0f * med);
            double sd64 = g_std64[tid];
            float thr2 = valid ? (float)((1.5 * sd64) * (1.5 * sd64)) : -1.0f;
            g_valid[tid] = valid;
            g_ktab[tid]  = make_float2((float)g_tn64[tid], thr2);
        }
    }
    __threadfence();
    grid.sync();

    // ================= PHASE C: MFMA bulk min pass (templates staged ONCE per CU) =======
    {
        for (int idx = tid * 8; idx < NCLUST * NFEAT; idx += 1024 * 8)
            *(short8v*)&sm.c.tml[idx] = *(const short8v*)&g_tmplbf[idx];
        if (tid < NCLUST) sm.c.ktab[tid] = g_ktab[tid];
        __syncthreads();

        const int row = lane & 15, grp = lane >> 4;
        const int ntiles = (n + 1023) >> 10;          // 1024 spikes per block-tile

        for (int tile = bid; tile < ntiles; tile += NBLK) {
            const int tbase = tile * 1024;
            const int i0w   = tbase + wave * 64;

            #pragma unroll 1
            for (int sb = 0; sb < 4; ++sb) {
                const int i0 = i0w + sb * 16;

                int ri = i0 + row;
                int rc = (ri < n) ? ri : (n - 1);
                const float* sp = spikes + (size_t)rc * NFEAT + grp * 8;
                float4 a0 = *(const float4*)(sp);
                float4 a1 = *(const float4*)(sp + 4);
                float4 a2 = *(const float4*)(sp + 32);
                float4 a3 = *(const float4*)(sp + 36);
                short8v af0, af1;
                af0[0] = (short)f2bf(a0.x); af0[1] = (short)f2bf(a0.y);
                af0[2] = (short)f2bf(a0.z); af0[3] = (short)f2bf(a0.w);
                af0[4] = (short)f2bf(a1.x); af0[5] = (short)f2bf(a1.y);
                af0[6] = (short)f2bf(a1.z); af0[7] = (short)f2bf(a1.w);
                af1[0] = (short)f2bf(a2.x); af1[1] = (short)f2bf(a2.y);
                af1[2] = (short)f2bf(a2.z); af1[3] = (short)f2bf(a2.w);
                af1[4] = (short)f2bf(a3.x); af1[5] = (short)f2bf(a3.y);
                af1[6] = (short)f2bf(a3.z); af1[7] = (short)f2bf(a3.w);

                float pss = a0.x*a0.x + a0.y*a0.y + a0.z*a0.z + a0.w*a0.w
                          + a1.x*a1.x + a1.y*a1.y + a1.z*a1.z + a1.w*a1.w
                          + a2.x*a2.x + a2.y*a2.y + a2.z*a2.z + a2.w*a2.w
                          + a3.x*a3.x + a3.y*a3.y + a3.z*a3.z + a3.w*a3.w;
                pss += __shfl_xor(pss, 16);
                pss += __shfl_xor(pss, 32);

                float snr[4];
                #pragma unroll
                for (int r = 0; r < 4; ++r) snr[r] = __shfl(pss, grp * 4 + r);

                float d2min[4] = {3.4e38f, 3.4e38f, 3.4e38f, 3.4e38f};

                #pragma unroll 2
                for (int nt = 0; nt < 16; ++nt) {
                    int c = nt * 16 + row;
                    unsigned co = (unsigned)c * 128u;
                    unsigned sw = (((unsigned)c & 7u) << 4);
                    short8v b0 = *(short8v*)((char*)sm.c.tml + (co + (((unsigned)grp * 16u) ^ sw)));
                    short8v b1 = *(short8v*)((char*)sm.c.tml + (co + ((((unsigned)grp + 4u) * 16u) ^ sw)));
                    float4v acc = {0.f, 0.f, 0.f, 0.f};
                    acc = __builtin_amdgcn_mfma_f32_16x16x32_bf16(af0, b0, acc, 0, 0, 0);
                    acc = __builtin_amdgcn_mfma_f32_16x16x32_bf16(af1, b1, acc, 0, 0, 0);
                    float2 kt = sm.c.ktab[c];
                    #pragma unroll
                    for (int r = 0; r < 4; ++r) {
                        float d2 = (snr[r] - 2.0f * acc[r]) + kt.x;
                        if (!(d2 > kt.y)) d2min[r] = fminf(d2min[r], d2);
                    }
                }

                #pragma unroll
                for (int o = 1; o < 16; o <<= 1) {
                    #pragma unroll
                    for (int r = 0; r < 4; ++r) d2min[r] = fminf(d2min[r], __shfl_xor(d2min[r], o));
                }
                if (row == 0) {
                    #pragma unroll
                    for (int r = 0; r < 4; ++r) {
                        int i = i0 + grp * 4 + r;
                        if (i < n) {
                            float dm = d2min[r];
                            out[2 * (size_t)n + i] = (dm > 1e37f) ? BIGF : sqrtf(fmaxf(dm, 0.f));
                        }
                    }
                }
            }

            // pass-through + unmatched list (1024 threads cover the tile's 1024 spikes)
            int i = tbase + tid;
            if (i < n) {
                int si = sidx[i];
                out[i]             = (float)si;
                out[(size_t)n + i] = midx[i] ? 1.0f : 0.0f;
                if (si == 0) {
                    int p = atomicAdd(&g_nlist, 1);
                    if (p < 1000000) g_list[p] = i;
                }
            }
        }
    }
    __threadfence();
    grid.sync();

    // ================= PHASE D: precise f64 argmin (lane = cluster) =====================
    {
        double tn[4], thr[4]; int vld[4];
        #pragma unroll
        for (int q = 0; q < 4; ++q) {
            int c = q * 64 + lane;
            tn[q]  = g_tn64[c];
            thr[q] = 1.5 * g_std64[c];
            vld[q] = g_valid[c];
        }

        const int gwave = bid * 16 + wave;
        const int nwave = NBLK * 16;
        const int nt    = g_nlist;

        for (int t = gwave; t < nt; t += nwave) {
            const int i = g_list[t];
            const double sf = (double)spikes[(size_t)i * NFEAT + lane];

            double sn = sf * sf;
            #pragma unroll
            for (int o = 32; o; o >>= 1) sn += __shfl_xor(sn, o);

            double d0 = 0.0, d1 = 0.0, d2a = 0.0, d3 = 0.0;
            #pragma unroll 16
            for (int f = 0; f < NFEAT; ++f) {
                double b = __shfl(sf, f);
                const double* mrow = &g_means64T[(size_t)f * NCLUST + lane];
                d0  = fma(b, mrow[0],   d0);
                d1  = fma(b, mrow[64],  d1);
                d2a = fma(b, mrow[128], d2a);
                d3  = fma(b, mrow[192], d3);
            }
            double dot[4] = {d0, d1, d2a, d3};

            double dmin = 1e30; int best = 0;
            #pragma unroll
            for (int q = 0; q < 4; ++q) {        // ascending q => ascending cluster id
                if (!vld[q]) continue;
                double d2 = (sn - 2.0 * dot[q]) + tn[q];
                double dist = sqrt(fmax(d2, 0.0));
                if (dist > thr[q]) continue;
                if (dist < dmin) { dmin = dist; best = q * 64 + lane + 1; }
            }

            #pragma unroll
            for (int o = 32; o; o >>= 1) {
                double od = __shfl_xor(dmin, o);
                int    ob = __shfl_xor(best, o);
                if (od < dmin || (od == dmin && ob < best)) { dmin = od; best = ob; }
            }

            if (dmin >= 256.0) best = 0;   // FIRST_MATCH_MAX_DIST * N_SAMPLES

            if (lane == 0) {
                out[i]                 = (float)best;
                out[(size_t)n + i]     = (best != 0) ? 1.0f : 0.0f;
                out[2 * (size_t)n + i] = (float)dmin;
            }
        }
    }
}

extern "C" void kernel_launch(void* const* d_in, const int* in_sizes, int n_in,
                              void* d_out, int out_size, void* d_ws, size_t ws_size,
                              hipStream_t stream) {
    const float*         spikes = (const float*)d_in[0];
    const int*           sidx   = (const int*)d_in[1];
    const unsigned char* midx   = (const unsigned char*)d_in[2];
    float*               out    = (float*)d_out;
    int n = in_sizes[1];

    void* args[] = { (void*)&spikes, (void*)&sidx, (void*)&midx, (void*)&out, (void*)&n };
    hipLaunchCooperativeKernel((const void*)kfused, dim3(NBLK), dim3(1024), args, 0, stream);
}

// Round 14
// 205.448 us; speedup vs baseline: 3.7818x; 3.7818x over previous
//
#include <hip/hip_runtime.h>

#define NCLUST 256      // clusters 1..256 (cluster 0 = CLID_UNMATCHED, excluded)
#define NFEAT  64
#define NBLK_A 256      // 1 block/CU
#define BIGF   1e30f

#define SUMSC  16777216.0f      // 2^24 (pow2 mul = exact exponent shift)
#define SSQSC  2097152.0f       // 2^21
#define INV_SUMSC (1.0 / 16777216.0)
#define INV_SSQSC (1.0 / 2097152.0)

typedef __attribute__((ext_vector_type(8))) short  short8v;   // 8 x bf16
typedef __attribute__((ext_vector_type(4))) float  float4v;
typedef unsigned long long u64;

// ---- static device scratch (rewritten fully every call) ----
// u32 fixed-point partials (FEATURE-PERMUTED: word (f&1)*32 + (f>>1) per cluster row)
__device__ __align__(16) unsigned g_psum[(size_t)NCLUST * NBLK_A * NFEAT]; // 16.7MB
__device__ __align__(16) unsigned g_pssq[(size_t)NCLUST * NBLK_A * NFEAT]; // 16.7MB
__device__ unsigned g_pcnt[NCLUST * NBLK_A * 8];
__device__ float  g_cnt[NCLUST];
__device__ __align__(16) double g_means64[NCLUST * NFEAT];
__device__ __align__(16) double g_means64T[NFEAT * NCLUST];   // transposed [f][c]
__device__ __align__(16) unsigned short g_tmplbf[NCLUST * NFEAT]; // swizzled bf16 templates
__device__ double g_tn64[NCLUST];
__device__ double g_std64[NCLUST];
__device__ float  g_std32[NCLUST];
__device__ float2 g_ktab[NCLUST];         // (tn_f32, thr2_f32 or -1 if invalid)
__device__ int    g_valid[NCLUST];
__device__ int    g_list[1000000];
__device__ int    g_nlist;

static __device__ __forceinline__ unsigned short f2bf(float x) {
    union { float f; unsigned u; } v; v.f = x;
    unsigned r = v.u + 0x7fffu + ((v.u >> 16) & 1u);   // RNE
    return (unsigned short)(r >> 16);
}

// ---------------- A: segment sums, u32 fire-and-forget LDS atomics ----------------
// Permuted layout word(f) = (f&1)*32 + (f>>1): .x atomics hit banks 0..31 one
// lane each per half (2-way across halves = free), .y likewise. 32-spike batch.
__global__ __launch_bounds__(1024, 4) void kstats(const float* __restrict__ spikes,
                                                  const int* __restrict__ sidx, int n) {
    __shared__ unsigned lsum[NCLUST * NFEAT]; // 64 KiB  fixed-point 2^24 (permuted)
    __shared__ unsigned lssq[NCLUST * NFEAT]; // 64 KiB  fixed-point 2^21 (permuted)
    __shared__ unsigned lcnt[NCLUST * 8];     // 8 KiB
    for (int idx = threadIdx.x; idx < NCLUST * NFEAT; idx += 1024) { lsum[idx] = 0u; lssq[idx] = 0u; }
    for (int idx = threadIdx.x; idx < NCLUST * 8; idx += 1024) lcnt[idx] = 0u;
    __syncthreads();

    const int lane = threadIdx.x & 63;
    const int wave = threadIdx.x >> 6;          // 0..15
    const int half = lane >> 5;                 // 0/1: which spike of the pair
    const int m    = lane & 31;                 // feature pair index (feats 2m, 2m+1)
    const int per  = (n + gridDim.x - 1) / gridDim.x;
    const int s0   = blockIdx.x * per;
    const int s1   = min(n, s0 + per);

    for (int ib = s0 + wave * 32; ib < s1; ib += 16 * 32) {   // 16 pairs = 32 spikes/wave/iter
        float2 v[16]; int cc[16];
        #pragma unroll
        for (int p = 0; p < 16; ++p) {
            int i  = ib + p * 2 + half;
            int rc = (i < s1) ? i : (s1 - 1);
            v[p]  = *(const float2*)(spikes + (size_t)rc * NFEAT + m * 2);
            cc[p] = (i < s1) ? sidx[i] : 0;
        }
        #pragma unroll
        for (int p = 0; p < 16; ++p) {
            int c = cc[p];
            if (c != 0) {                        // per-half predication; atomics exec-masked
                int base = (c - 1) * NFEAT;
                atomicAdd(&lsum[base + m],      (unsigned)__float2int_rn(v[p].x * SUMSC));
                atomicAdd(&lsum[base + 32 + m], (unsigned)__float2int_rn(v[p].y * SUMSC));
                atomicAdd(&lssq[base + m],      (unsigned)__float2int_rn(v[p].x * v[p].x * SSQSC));
                atomicAdd(&lssq[base + 32 + m], (unsigned)__float2int_rn(v[p].y * v[p].y * SSQSC));
                if (m == 0) atomicAdd(&lcnt[(c - 1) * 8 + (wave & 7)], 1u);
            }
        }
    }
    __syncthreads();

    const int b = blockIdx.x;
    for (int idx = threadIdx.x; idx < NCLUST * NFEAT; idx += 1024) {
        int c = idx >> 6, w = idx & 63;
        g_psum[((size_t)c * NBLK_A + b) * NFEAT + w] = lsum[idx];   // stays permuted
        g_pssq[((size_t)c * NBLK_A + b) * NFEAT + w] = lssq[idx];
    }
    for (int idx = threadIdx.x; idx < NCLUST * 8; idx += 1024) {
        int c = idx >> 3, k = idx & 7;
        g_pcnt[(c * NBLK_A + b) * 8 + k] = lcnt[idx];
    }
}

// ---------------- A2: exact integer reduce -> f64 means / tn / std + bf16 templates ----------------
__global__ __launch_bounds__(256) void kfinal() {
    const int c = blockIdx.x;                 // cluster c+1
    __shared__ long long red [4][NFEAT];
    __shared__ long long redq[4][NFEAT];
    __shared__ double smean[NFEAT];
    __shared__ double sh_cnt;
    const int f = threadIdx.x & 63, j = threadIdx.x >> 6;
    const int w = ((f & 1) << 5) | (f >> 1);  // permuted word for feature f

    long long acc = 0, accq = 0;
    for (int b = j; b < NBLK_A; b += 4) {
        acc  += (int)g_psum[((size_t)c * NBLK_A + b) * NFEAT + w];   // same 256B segment/(c,b)
        accq += (int)g_pssq[((size_t)c * NBLK_A + b) * NFEAT + w];
    }
    red[j][f] = acc; redq[j][f] = accq;

    if (threadIdx.x < 64) {
        unsigned cn = 0u;
        for (int e = threadIdx.x; e < NBLK_A * 8; e += 64)
            cn += g_pcnt[c * NBLK_A * 8 + e];
        #pragma unroll
        for (int o = 32; o; o >>= 1) cn += __shfl_xor(cn, o);
        if (threadIdx.x == 0) sh_cnt = (double)cn;
    }
    __syncthreads();

    if (threadIdx.x < NFEAT) {
        long long tot = ((red[0][f] + red[1][f]) + red[2][f]) + red[3][f];
        double cnt = sh_cnt;
        double mean = (cnt > 0.0) ? ((double)tot * INV_SUMSC) / cnt : 0.0;
        g_means64[c * NFEAT + f]   = mean;
        g_means64T[f * NCLUST + c] = mean;
        smean[f] = mean;
        redq[0][f] = ((redq[0][f] + redq[1][f]) + redq[2][f]) + redq[3][f];
        // bf16 template write, swizzled layout
        unsigned short hb = f2bf((float)mean);
        unsigned g = (unsigned)(f >> 3);
        unsigned byteoff = (unsigned)c * 128u
                         + (((g * 16u) ^ (((unsigned)c & 7u) << 4)) + (unsigned)(f & 7) * 2u);
        *(unsigned short*)((char*)g_tmplbf + byteoff) = hb;
    }
    __syncthreads();
    if (threadIdx.x == 0) {
        double tn = 0.0; long long qs = 0;
        for (int q = 0; q < NFEAT; ++q) { tn += smean[q] * smean[q]; qs += redq[0][q]; }
        double cnt = sh_cnt;
        double var = (cnt > 0.0) ? ((double)qs * INV_SSQSC) / cnt - tn : 0.0;
        if (var < 0.0) var = 0.0;
        double sd = sqrt(var);
        g_tn64[c] = tn; g_std64[c] = sd; g_std32[c] = (float)sd;
        g_cnt[c] = (float)cnt;
    }
}

// ---------------- A3: median, validity, thresholds (tiny serial kernel) ----------------
__global__ __launch_bounds__(256) void kmedian() {
    __shared__ float svals[NCLUST];
    __shared__ int   svalid[NCLUST];
    __shared__ float mred[2];
    int t = threadIdx.x;
    if (t == 0) { mred[0] = 0.f; mred[1] = 0.f; g_nlist = 0; }
    float cnt = g_cnt[t];
    int v0 = (cnt > 0.f) ? 1 : 0;
    float sd = g_std32[t];
    svals[t] = sd; svalid[t] = v0;
    __syncthreads();

    int m = 0, rank = 0;
    for (int jj = 0; jj < NCLUST; ++jj) {
        if (svalid[jj]) {
            ++m;
            float sj = svals[jj];
            if (sj < sd || (sj == sd && jj < t)) ++rank;
        }
    }
    if (v0) {
        if (rank == (m - 1) / 2) mred[0] = sd;
        if (rank == m / 2)       mred[1] = sd;
    }
    __syncthreads();
    float med = 0.5f * (mred[0] + mred[1]);

    int valid = v0 && (sd <= 3.0f * med);
    double sd64 = g_std64[t];
    float thr2 = valid ? (float)((1.5 * sd64) * (1.5 * sd64)) : -1.0f;
    g_valid[t] = valid;
    g_ktab[t]  = make_float2((float)g_tn64[t], thr2);
}

// ---------------- C: MFMA bulk min pass, 256 spikes per block ----------------
// mfma_f32_16x16x32_bf16: A lane l -> row=l&15, k=(l>>4)*8+j ; B lane l -> col=l&15, same k map.
// D lane l, reg r -> row=(l>>4)*4+r, col=l&15  [verified layout, m89]
__global__ __launch_bounds__(256) void kmatch(const float* __restrict__ spikes,
                                              const int* __restrict__ sidx,
                                              const unsigned char* __restrict__ midx,
                                              float* __restrict__ out, int n) {
    __shared__ __align__(16) unsigned short tml[NCLUST * NFEAT]; // 32 KiB swizzled bf16
    __shared__ float2 ktab_sh[NCLUST];

    // stage pre-swizzled templates: linear 16B copies
    for (int idx = threadIdx.x * 8; idx < NCLUST * NFEAT; idx += 256 * 8)
        *(short8v*)&tml[idx] = *(const short8v*)&g_tmplbf[idx];
    if (threadIdx.x < NCLUST) ktab_sh[threadIdx.x] = g_ktab[threadIdx.x];
    __syncthreads();

    const int lane = threadIdx.x & 63, wave = threadIdx.x >> 6;
    const int row  = lane & 15, grp = lane >> 4;
    const int i0w  = blockIdx.x * 256 + wave * 64;   // this wave's 64 spikes

    #pragma unroll 1
    for (int sb = 0; sb < 4; ++sb) {
        const int i0 = i0w + sb * 16;

        // ---- A fragments (spikes straight from global, f32 -> bf16) ----
        int ri = i0 + row;
        int rc = (ri < n) ? ri : (n - 1);
        const float* sp = spikes + (size_t)rc * NFEAT + grp * 8;
        float4 a0 = *(const float4*)(sp);
        float4 a1 = *(const float4*)(sp + 4);
        float4 a2 = *(const float4*)(sp + 32);
        float4 a3 = *(const float4*)(sp + 36);
        short8v af0, af1;
        af0[0] = (short)f2bf(a0.x); af0[1] = (short)f2bf(a0.y);
        af0[2] = (short)f2bf(a0.z); af0[3] = (short)f2bf(a0.w);
        af0[4] = (short)f2bf(a1.x); af0[5] = (short)f2bf(a1.y);
        af0[6] = (short)f2bf(a1.z); af0[7] = (short)f2bf(a1.w);
        af1[0] = (short)f2bf(a2.x); af1[1] = (short)f2bf(a2.y);
        af1[2] = (short)f2bf(a2.z); af1[3] = (short)f2bf(a2.w);
        af1[4] = (short)f2bf(a3.x); af1[5] = (short)f2bf(a3.y);
        af1[6] = (short)f2bf(a3.z); af1[7] = (short)f2bf(a3.w);

        // sn (|s|^2) in f32 from ORIGINAL f32 values; reduce across the 4 k-groups
        float pss = a0.x*a0.x + a0.y*a0.y + a0.z*a0.z + a0.w*a0.w
                  + a1.x*a1.x + a1.y*a1.y + a1.z*a1.z + a1.w*a1.w
                  + a2.x*a2.x + a2.y*a2.y + a2.z*a2.z + a2.w*a2.w
                  + a3.x*a3.x + a3.y*a3.y + a3.z*a3.z + a3.w*a3.w;
        pss += __shfl_xor(pss, 16);
        pss += __shfl_xor(pss, 32);          // now sn of row `row` on every lane

        float snr[4];
        #pragma unroll
        for (int r = 0; r < 4; ++r) snr[r] = __shfl(pss, grp * 4 + r);

        float d2min[4] = {3.4e38f, 3.4e38f, 3.4e38f, 3.4e38f};

        #pragma unroll 2
        for (int nt = 0; nt < 16; ++nt) {
            int c = nt * 16 + row;
            unsigned co = (unsigned)c * 128u;
            unsigned sw = (((unsigned)c & 7u) << 4);
            short8v b0 = *(short8v*)((char*)tml + (co + (((unsigned)grp * 16u) ^ sw)));
            short8v b1 = *(short8v*)((char*)tml + (co + ((((unsigned)grp + 4u) * 16u) ^ sw)));
            float4v acc = {0.f, 0.f, 0.f, 0.f};
            acc = __builtin_amdgcn_mfma_f32_16x16x32_bf16(af0, b0, acc, 0, 0, 0);
            acc = __builtin_amdgcn_mfma_f32_16x16x32_bf16(af1, b1, acc, 0, 0, 0);
            float2 kt = ktab_sh[c];
            #pragma unroll
            for (int r = 0; r < 4; ++r) {
                float d2 = (snr[r] - 2.0f * acc[r]) + kt.x;
                if (!(d2 > kt.y)) d2min[r] = fminf(d2min[r], d2);  // thr2=-1 => masked
            }
        }

        // min over the 16 cluster-lanes (xor 1,2,4,8)
        #pragma unroll
        for (int o = 1; o < 16; o <<= 1) {
            #pragma unroll
            for (int r = 0; r < 4; ++r) d2min[r] = fminf(d2min[r], __shfl_xor(d2min[r], o));
        }
        if (row == 0) {
            #pragma unroll
            for (int r = 0; r < 4; ++r) {
                int i = i0 + grp * 4 + r;
                if (i < n) {
                    float dm = d2min[r];
                    out[2 * (size_t)n + i] = (dm > 1e37f) ? BIGF : sqrtf(fmaxf(dm, 0.f));
                }
            }
        }
    }

    // pass-through outputs + unmatched list (256 threads cover this block's 256 spikes)
    int i = blockIdx.x * 256 + threadIdx.x;
    if (i < n) {
        int si = sidx[i];
        out[i]             = (float)si;
        out[(size_t)n + i] = midx[i] ? 1.0f : 0.0f;
        if (si == 0) {
            int p = atomicAdd(&g_nlist, 1);
            if (p < 1000000) g_list[p] = i;
        }
    }
}

// ---------------- D: precise f64 argmin, LANE = CLUSTER ----------------
__global__ __launch_bounds__(256) void kprecise(const float* __restrict__ spikes,
                                                float* __restrict__ out, int n) {
    const int lane  = threadIdx.x & 63;
    const int gwave = (blockIdx.x * 256 + threadIdx.x) >> 6;
    const int nwave = (gridDim.x * 256) >> 6;
    const int nt    = g_nlist;

    // per-lane cluster constants (c = q*64 + lane), coalesced loads
    double tn[4], thr[4]; int vld[4];
    #pragma unroll
    for (int q = 0; q < 4; ++q) {
        int c = q * 64 + lane;
        tn[q]  = g_tn64[c];
        thr[q] = 1.5 * g_std64[c];
        vld[q] = g_valid[c];
    }

    for (int t = gwave; t < nt; t += nwave) {
        const int i = g_list[t];
        const double sf = (double)spikes[(size_t)i * NFEAT + lane];

        double sn = sf * sf;                 // once per spike
        #pragma unroll
        for (int o = 32; o; o >>= 1) sn += __shfl_xor(sn, o);

        double d0 = 0.0, d1 = 0.0, d2a = 0.0, d3 = 0.0;
        #pragma unroll 16
        for (int f = 0; f < NFEAT; ++f) {
            double b = __shfl(sf, f);        // independent across f
            const double* mrow = &g_means64T[(size_t)f * NCLUST + lane];
            d0 = fma(b, mrow[0],   d0);
            d1 = fma(b, mrow[64],  d1);
            d2a = fma(b, mrow[128], d2a);
            d3 = fma(b, mrow[192], d3);
        }
        double dot[4] = {d0, d1, d2a, d3};

        double dmin = 1e30; int best = 0;
        #pragma unroll
        for (int q = 0; q < 4; ++q) {        // ascending q => ascending cluster id
            if (!vld[q]) continue;
            double d2 = (sn - 2.0 * dot[q]) + tn[q];
            double dist = sqrt(fmax(d2, 0.0));
            if (dist > thr[q]) continue;
            if (dist < dmin) { dmin = dist; best = q * 64 + lane + 1; }
        }

        // cross-lane argmin with first-index tie-break
        #pragma unroll
        for (int o = 32; o; o >>= 1) {
            double od = __shfl_xor(dmin, o);
            int    ob = __shfl_xor(best, o);
            if (od < dmin || (od == dmin && ob < best)) { dmin = od; best = ob; }
        }

        if (dmin >= 256.0) best = 0;   // FIRST_MATCH_MAX_DIST * N_SAMPLES

        if (lane == 0) {
            out[i]                 = (float)best;
            out[(size_t)n + i]     = (best != 0) ? 1.0f : 0.0f;
            out[2 * (size_t)n + i] = (float)dmin;
        }
    }
}

extern "C" void kernel_launch(void* const* d_in, const int* in_sizes, int n_in,
                              void* d_out, int out_size, void* d_ws, size_t ws_size,
                              hipStream_t stream) {
    const float*         spikes = (const float*)d_in[0];
    const int*           sidx   = (const int*)d_in[1];
    const unsigned char* midx   = (const unsigned char*)d_in[2];
    float*               out    = (float*)d_out;
    const int n = in_sizes[1];

    kstats<<<NBLK_A, 1024, 0, stream>>>(spikes, sidx, n);
    kfinal<<<NCLUST, 256, 0, stream>>>();
    kmedian<<<1, 256, 0, stream>>>();
    int nblk = (n + 255) / 256;
    kmatch<<<nblk, 256, 0, stream>>>(spikes, sidx, midx, out, n);
    kprecise<<<1024, 256, 0, stream>>>(spikes, out, n);
}